// Round 7
// baseline (378.060 us; speedup 1.0000x reference)
//
#include <hip/hip_runtime.h>
#include <cstdint>

#define B_ROWS 8192
#define KDIM 1024
#define N4 4096

typedef __attribute__((ext_vector_type(8))) short short8;
typedef __attribute__((ext_vector_type(4))) float float4v;

__device__ __forceinline__ unsigned short f2bf(float f) {
  union { float f; unsigned int u; } v; v.f = f;
  unsigned int r = v.u + 0x7fffu + ((v.u >> 16) & 1u);  // RNE
  return (unsigned short)(r >> 16);
}

__device__ __forceinline__ float bf2f(unsigned short s) {
  union { unsigned int u; float f; } v; v.u = ((unsigned int)s) << 16;
  return v.f;
}

__device__ __forceinline__ void async16(const unsigned short* g, unsigned short* l) {
  auto gp = (const __attribute__((address_space(1))) unsigned int*)(uintptr_t)g;
  auto lp = (__attribute__((address_space(3))) unsigned int*)(unsigned int)(uintptr_t)l;
  __builtin_amdgcn_global_load_lds(gp, lp, 16, 0, 0);
}

// fast transcendentals: v_exp_f32 (2^x) + v_rcp_f32; rel err ~1e-6,
// negligible vs bf16-GEMM absmax 0.031.
__device__ __forceinline__ float sigm(float v) {
  return __builtin_amdgcn_rcpf(1.f + __builtin_amdgcn_exp2f(-1.44269504088896f * v));
}
__device__ __forceinline__ float tanh_f(float v) {
  return 1.f - 2.f * __builtin_amdgcn_rcpf(1.f + __builtin_amdgcn_exp2f(2.88539008177793f * v));
}

// ---------------- merged prep: casts + weight transposes (one dispatch) -----

__global__ __launch_bounds__(256) void prep(
    const float* __restrict__ h0, const float* __restrict__ x,
    unsigned short* __restrict__ Ah, unsigned short* __restrict__ Ax,
    const float* __restrict__ Wh, const float* __restrict__ Wx,
    unsigned short* __restrict__ Wth, unsigned short* __restrict__ Wtx) {
  __shared__ float tile[32][33];
  const int bid = blockIdx.x;
  if (bid < 16384) {
    const float* in = (bid >= 8192) ? x : h0;
    unsigned short* out = (bid >= 8192) ? Ax : Ah;
    int i = ((bid & 8191) * 256 + threadIdx.x) * 4;
    float4 v = *(const float4*)(in + i);
    ushort4 o;
    o.x = f2bf(v.x); o.y = f2bf(v.y); o.z = f2bf(v.z); o.w = f2bf(v.w);
    *(ushort4*)(out + i) = o;
  } else {
    int b2 = bid - 16384;
    const float* W = (b2 >= 4096) ? Wx : Wh;
    unsigned short* Wt = (b2 >= 4096) ? Wtx : Wth;
    int r = b2 & 4095;
    int n0 = (r & 127) * 32;
    int k0 = (r >> 7) * 32;
    int tx = threadIdx.x & 31;
    int ty = threadIdx.x >> 5;
#pragma unroll
    for (int i = 0; i < 32; i += 8)
      tile[ty + i][tx] = W[(size_t)(k0 + ty + i) * N4 + n0 + tx];
    __syncthreads();
#pragma unroll
    for (int i = 0; i < 32; i += 8)
      Wt[(size_t)(n0 + ty + i) * KDIM + k0 + tx] = f2bf(tile[tx][ty + i]);
  }
}

// ---------------- bf16 MFMA GEMM, 256x256 tile, 4 waves of 128x128 ----------
// C[256][256] = A[256,K]*Wt[256,K]^T.  256 thr = 4 waves (2M x 2N), wave tile
// 128x128: acc[8][8] f32x4 = 256 VGPR.  1 wave/SIMD; ILP from 64 indep accs.
// LDS 128 KiB: A,B each 2 x (256x64) bf16, double buffered.
// WHY this shape: per K-tile per CU, MFMA floor = 128 MFMA/SIMD x 19.4 cyc
// = 2483; LDS-unit demand = 128 ds_read_b128 x 12 + ~512 DMA-write = ~2048
// < 2483.  The old 128x64 wave tile had 192 reads (~2816 cyc) -> LDS unit
// oversubscribed; that, not barrier placement, was the 43% plateau.
// Rotation swizzle: physical 16B slot c of row r holds logical chunk (c-r)&7;
// global_load_lds keeps linear LDS dest, permutes global source chunk.
//
// Schedule per tile t (R6 skeleton, ledger-verified, never drains vmcnt):
//   stage A(t+1)->other A-buf (8 DMA);
//   ds_read aF(kh0) 8 + bFa(kh0) 8 + bFb(kh1) 8 [pre-read for WAR];
//   64 MFMA kh0; lgkmcnt(0)+barrier [cur-B reads done];
//   stage B(t+2)->current B-buf (8 DMA);
//   ds_read aF(kh1) 8 [cur-A, not written this tile];
//   64 MFMA kh1; vmcnt(8)+barrier.
// Ledger: outstanding at tile end = B(t+1)8 + A(t+1)8 + B(t+2)8 = 24;
// vmcnt(8) forces the 16 oldest = exactly tile t+1's operands.

#define LGKM0()  asm volatile("s_waitcnt lgkmcnt(0)" ::: "memory")
#define SCHED0() __builtin_amdgcn_sched_barrier(0)
#define BARRIER() __builtin_amdgcn_s_barrier()

__device__ __forceinline__ void stage8(const unsigned short* gp, unsigned short* lb, int kk) {
#pragma unroll
  for (int j = 0; j < 8; ++j)
    async16(gp + kk + j * 8 * KDIM, lb + j * 8 * 64);
}

__global__ __launch_bounds__(256, 1) void gemm_bf16(
    const unsigned short* __restrict__ Ah, const unsigned short* __restrict__ Wth,
    unsigned short* __restrict__ Uh,
    const unsigned short* __restrict__ Ax, const unsigned short* __restrict__ Wtx,
    unsigned short* __restrict__ Ux, int row0) {
  const unsigned short* A; const unsigned short* W; unsigned short* U;
  if (blockIdx.z == 0) { A = Ah; W = Wth; U = Uh; } else { A = Ax; W = Wtx; U = Ux; }

  __shared__ unsigned short ldsA[2 * 256 * 64];
  __shared__ unsigned short ldsB[2 * 256 * 64];

  const int tid = threadIdx.x;
  const int wave = tid >> 6;      // 0..3
  const int lane = tid & 63;
  const int wm = (wave & 1) * 128;   // M half
  const int wn = (wave >> 1) * 128;  // N half

  // bijective XCD swizzle (m204); nwg = 16 * 32 = 512, divisible by 8
  const int gx = N4 / 256;  // 16
  const int nwg = gx * (int)gridDim.y;
  const int f = (int)blockIdx.y * gx + (int)blockIdx.x;
  const int qq = nwg >> 3, rr = nwg & 7;
  const int xcd = f & 7, idx = f >> 3;
  const int wg = (xcd < rr) ? (xcd * (qq + 1) + idx)
                            : (rr * (qq + 1) + (xcd - rr) * qq + idx);
  const int bx = wg & (gx - 1);
  const int by = wg / gx;

  const int m0 = row0 + by * 256;
  const int n0 = bx * 256;

  // staging: one async16 covers 8 rows (64 lanes x 16B); 8 slices per wave
  const int r8 = lane >> 3;
  const int c8 = lane & 7;
  const int g8 = ((c8 - r8) & 7) * 8;  // logical chunk to fetch (elem offset)
  const int aR = wave * 64;  // A rows staged by this wave
  const int bR = wave * 64;  // B rows staged by this wave

  const unsigned short* gA = A + (size_t)(m0 + aR + r8) * KDIM + g8;
  const unsigned short* gB = W + (size_t)(n0 + bR + r8) * KDIM + g8;

  // fragment offsets: row = base + i*16 + lq, chunk q = kh*4 + lh,
  // physical slot (q+row)&7 = (q+lq)&7 (bases are multiples of 8)
  const int lq = lane & 15, lh = lane >> 4;
  const int offA0 = (wm + lq) * 64 + ((lh + lq) & 7) * 8;
  const int offA1 = (wm + lq) * 64 + ((4 + lh + lq) & 7) * 8;
  const int offB0 = (wn + lq) * 64 + ((lh + lq) & 7) * 8;
  const int offB1 = (wn + lq) * 64 + ((4 + lh + lq) & 7) * 8;

  float4v acc[8][8];
  float4v zero = {0.f, 0.f, 0.f, 0.f};
#pragma unroll
  for (int i = 0; i < 8; ++i)
#pragma unroll
    for (int j = 0; j < 8; ++j) acc[i][j] = zero;

  // prologue: B(0)->bufB0, A(0)->bufA0, B(1)->bufB1; force B(0),A(0)
  stage8(gB, ldsB + bR * 64, 0);
  stage8(gA, ldsA + aR * 64, 0);
  stage8(gB, ldsB + 16384 + bR * 64, 64);
  asm volatile("s_waitcnt vmcnt(8)\n\ts_barrier" ::: "memory");

  short8 aF[8], bFa[8], bFb[8];

  for (int t = 0; t < KDIM / 64; ++t) {
    const unsigned short* sA = ldsA + (t & 1) * 16384;
    const unsigned short* sB = ldsB + (t & 1) * 16384;
    unsigned short* nA = (unsigned short*)ldsA + ((t + 1) & 1) * 16384;
    unsigned short* cB = (unsigned short*)ldsB + (t & 1) * 16384;
    const int kA = (t + 1) * 64;   // ghost at t=15 stays inside d_ws
    const int kB = (t + 2) * 64;   // ghost at t>=14 stays inside d_ws

    // stage A(t+1) -> other A-buf (WAR-safe: t-1 readers done at t-entry)
    stage8(gA, nA + aR * 64, kA);

    // 24 ds_reads: kh0 A+B, plus kh1 B pre-read (WAR vs B(t+2) stage)
#pragma unroll
    for (int i = 0; i < 8; ++i) aF[i]  = *(const short8*)(sA + offA0 + i * 1024);
#pragma unroll
    for (int j = 0; j < 8; ++j) bFa[j] = *(const short8*)(sB + offB0 + j * 1024);
#pragma unroll
    for (int j = 0; j < 8; ++j) bFb[j] = *(const short8*)(sB + offB1 + j * 1024);

    __builtin_amdgcn_s_setprio(1);
#pragma unroll
    for (int i = 0; i < 8; ++i)
#pragma unroll
      for (int j = 0; j < 8; ++j)
        acc[i][j] = __builtin_amdgcn_mfma_f32_16x16x32_bf16(aF[i], bFa[j], acc[i][j], 0, 0, 0);
    __builtin_amdgcn_s_setprio(0);

    // mid-barrier: all waves' cur-B reads complete -> cur-B writable
    LGKM0(); SCHED0();
    BARRIER();

    // stage B(t+2) -> current B-buf (its t+2 home)
    stage8(gB, cB + bR * 64, kB);

    // kh1 A frags from cur-A (not written this tile; reuses aF regs)
#pragma unroll
    for (int i = 0; i < 8; ++i) aF[i] = *(const short8*)(sA + offA1 + i * 1024);

    __builtin_amdgcn_s_setprio(1);
#pragma unroll
    for (int i = 0; i < 8; ++i)
#pragma unroll
      for (int j = 0; j < 8; ++j)
        acc[i][j] = __builtin_amdgcn_mfma_f32_16x16x32_bf16(aF[i], bFb[j], acc[i][j], 0, 0, 0);
    __builtin_amdgcn_s_setprio(0);

    // forces B(t+1),A(t+1); leaves B(t+2) in flight
    asm volatile("s_waitcnt vmcnt(8)\n\ts_barrier" ::: "memory");
  }
  asm volatile("s_waitcnt vmcnt(0)" ::: "memory");  // drain ghost stages

  // epilogue: C/D layout col = lane&15, row = (lane>>4)*4 + reg; store bf16
  const int colc = lane & 15;
  const int rowq = (lane >> 4) * 4;
  unsigned short* Ub = U + (size_t)(by * 256 + wm + rowq) * N4 + n0 + wn + colc;
#pragma unroll
  for (int mi = 0; mi < 8; ++mi)
#pragma unroll
    for (int r = 0; r < 4; ++r) {
      unsigned short* Urow = Ub + (size_t)(mi * 16 + r) * N4;
#pragma unroll
      for (int nj = 0; nj < 8; ++nj) Urow[nj * 16] = f2bf(acc[mi][nj][r]);
    }
}

// ---------------- fused LN + LSTM pointwise (bf16 U) ----------------

__global__ __launch_bounds__(256) void fused_ln_lstm(
    const unsigned short* __restrict__ Uh, const unsigned short* __restrict__ Ux,
    const float* __restrict__ c0, const float* __restrict__ bias,
    const float* __restrict__ g1, const float* __restrict__ b1,
    const float* __restrict__ g2, const float* __restrict__ b2,
    const float* __restrict__ g3, const float* __restrict__ b3,
    float* __restrict__ h1o, float* __restrict__ c1o, int row0) {
  const int t = threadIdx.x;
  const int lane = t & 63;
  const int wv = t >> 6;
  const size_t rloc = blockIdx.x;
  const size_t rabs = rloc + (size_t)row0;

  const ushort4* uh = (const ushort4*)(Uh + rloc * N4);
  const ushort4* ux = (const ushort4*)(Ux + rloc * N4);
  float4 cold = ((const float4*)(c0 + rabs * KDIM))[t];  // issue early

  float4 vh[4], vx[4];
  float sh = 0.f, qh = 0.f, sx = 0.f, qx = 0.f;
#pragma unroll
  for (int k = 0; k < 4; ++k) {
    ushort4 au = uh[k * 256 + t];
    float4 a; a.x = bf2f(au.x); a.y = bf2f(au.y); a.z = bf2f(au.z); a.w = bf2f(au.w);
    vh[k] = a;
    sh += (a.x + a.y) + (a.z + a.w);
    qh += a.x * a.x + a.y * a.y + a.z * a.z + a.w * a.w;
    ushort4 bu = ux[k * 256 + t];
    float4 b; b.x = bf2f(bu.x); b.y = bf2f(bu.y); b.z = bf2f(bu.z); b.w = bf2f(bu.w);
    vx[k] = b;
    sx += (b.x + b.y) + (b.z + b.w);
    qx += b.x * b.x + b.y * b.y + b.z * b.z + b.w * b.w;
  }
  __shared__ float red[4][4];
#pragma unroll
  for (int o = 32; o > 0; o >>= 1) {
    sh += __shfl_down(sh, o); qh += __shfl_down(qh, o);
    sx += __shfl_down(sx, o); qx += __shfl_down(qx, o);
  }
  if (lane == 0) { red[wv][0] = sh; red[wv][1] = qh; red[wv][2] = sx; red[wv][3] = qx; }
  __syncthreads();
  sh = red[0][0] + red[1][0] + red[2][0] + red[3][0];
  qh = red[0][1] + red[1][1] + red[2][1] + red[3][1];
  sx = red[0][2] + red[1][2] + red[2][2] + red[3][2];
  qx = red[0][3] + red[1][3] + red[2][3] + red[3][3];
  const float inv4 = 1.f / 4096.f;
  const float muh = sh * inv4, mux = sx * inv4;
  const float rsh = rsqrtf(qh * inv4 - muh * muh + 1e-5f);
  const float rsx = rsqrtf(qx * inv4 - mux * mux + 1e-5f);

  float4 gate[4];
#pragma unroll
  for (int k = 0; k < 4; ++k) {
    int j = k * 256 + t;
    float4 G1 = ((const float4*)g1)[j], B1 = ((const float4*)b1)[j];
    float4 G2 = ((const float4*)g2)[j], B2 = ((const float4*)b2)[j];
    float4 BB = ((const float4*)bias)[j];
    float4 a = vh[k], b = vx[k], r;
    r.x = (a.x - muh) * rsh * G1.x + B1.x + (b.x - mux) * rsx * G2.x + B2.x + BB.x;
    r.y = (a.y - muh) * rsh * G1.y + B1.y + (b.y - mux) * rsx * G2.y + B2.y + BB.y;
    r.z = (a.z - muh) * rsh * G1.z + B1.z + (b.z - mux) * rsx * G2.z + B2.z + BB.z;
    r.w = (a.w - muh) * rsh * G1.w + B1.w + (b.w - mux) * rsx * G2.w + B2.w + BB.w;
    gate[k] = r;
  }
  float4 fg = gate[0], ig = gate[1], og = gate[2], cg = gate[3];
  float4 c1v;
  c1v.x = sigm(fg.x) * cold.x + sigm(ig.x) * tanh_f(cg.x);
  c1v.y = sigm(fg.y) * cold.y + sigm(ig.y) * tanh_f(cg.y);
  c1v.z = sigm(fg.z) * cold.z + sigm(ig.z) * tanh_f(cg.z);
  c1v.w = sigm(fg.w) * cold.w + sigm(ig.w) * tanh_f(cg.w);

  float sc = (c1v.x + c1v.y) + (c1v.z + c1v.w);
  float qc = c1v.x * c1v.x + c1v.y * c1v.y + c1v.z * c1v.z + c1v.w * c1v.w;
#pragma unroll
  for (int o = 32; o > 0; o >>= 1) { sc += __shfl_down(sc, o); qc += __shfl_down(qc, o); }
  __syncthreads();  // protect `red` reuse
  if (lane == 0) { red[wv][0] = sc; red[wv][1] = qc; }
  __syncthreads();
  sc = red[0][0] + red[1][0] + red[2][0] + red[3][0];
  qc = red[0][1] + red[1][1] + red[2][1] + red[3][1];
  const float invH = 1.f / 1024.f;
  const float muc = sc * invH;
  const float rsc = rsqrtf(qc * invH - muc * muc + 1e-5f);
  float4 G3 = ((const float4*)g3)[t], B3 = ((const float4*)b3)[t];
  float4 h1v;
  h1v.x = sigm(og.x) * tanh_f((c1v.x - muc) * rsc * G3.x + B3.x);
  h1v.y = sigm(og.y) * tanh_f((c1v.y - muc) * rsc * G3.y + B3.y);
  h1v.z = sigm(og.z) * tanh_f((c1v.z - muc) * rsc * G3.z + B3.z);
  h1v.w = sigm(og.w) * tanh_f((c1v.w - muc) * rsc * G3.w + B3.w);

  ((float4*)(h1o + rabs * KDIM))[t] = h1v;
  ((float4*)(c1o + rabs * KDIM))[t] = c1v;
}

// ---------------- launch ----------------

extern "C" void kernel_launch(void* const* d_in, const int* in_sizes, int n_in,
                              void* d_out, int out_size, void* d_ws, size_t ws_size,
                              hipStream_t stream) {
  const float* x    = (const float*)d_in[0];
  const float* h0   = (const float*)d_in[1];
  const float* c0   = (const float*)d_in[2];
  const float* Wh   = (const float*)d_in[3];
  const float* Wx   = (const float*)d_in[4];
  const float* bias = (const float*)d_in[5];
  const float* g1   = (const float*)d_in[6];
  const float* b1   = (const float*)d_in[7];
  const float* g2   = (const float*)d_in[8];
  const float* b2   = (const float*)d_in[9];
  const float* g3   = (const float*)d_in[10];
  const float* b3   = (const float*)d_in[11];
  float* h1o = (float*)d_out;
  float* c1o = h1o + (size_t)B_ROWS * KDIM;

  // ws layout: Ah bf16 | Ax bf16 | Wth bf16 | Wtx bf16 | U (chunked bf16 gate bufs)
  unsigned short* Ah  = (unsigned short*)d_ws;
  unsigned short* Ax  = Ah + (size_t)B_ROWS * KDIM;
  unsigned short* Wth = Ax + (size_t)B_ROWS * KDIM;
  unsigned short* Wtx = Wth + (size_t)N4 * KDIM;
  unsigned short* U = Wtx + (size_t)N4 * KDIM;
  size_t used = ((size_t)B_ROWS * KDIM * 2 + (size_t)N4 * KDIM * 2) * sizeof(unsigned short);
  size_t rem = ws_size > used ? ws_size - used : 0;
  int chunk = (int)(rem / ((size_t)2 * N4 * sizeof(unsigned short)));
  chunk &= ~255;
  if (chunk > B_ROWS) chunk = B_ROWS;
  if (chunk < 256) chunk = 256;  // assume ws_size is at least ~64MB

  prep<<<24576, 256, 0, stream>>>(h0, x, Ah, Ax, Wh, Wx, Wth, Wtx);

  for (int r0 = 0; r0 < B_ROWS; r0 += chunk) {
    int rows = chunk;
    if (r0 + rows > B_ROWS) rows = B_ROWS - r0;
    unsigned short* Uh = U;
    unsigned short* Ux = U + (size_t)rows * N4;
    gemm_bf16<<<dim3(N4 / 256, rows / 256, 2), 256, 0, stream>>>(Ah, Wth, Uh, Ax, Wtx, Ux, r0);
    fused_ln_lstm<<<rows, 256, 0, stream>>>(Uh, Ux, c0, bias, g1, b1, g2, b2, g3, b3, h1o, c1o, r0);
  }
}

// Round 8
// 360.268 us; speedup vs baseline: 1.0494x; 1.0494x over previous
//
#include <hip/hip_runtime.h>
#include <cstdint>

#define B_ROWS 8192
#define KDIM 1024
#define N4 4096

typedef __attribute__((ext_vector_type(8))) short short8;
typedef __attribute__((ext_vector_type(4))) float float4v;

__device__ __forceinline__ unsigned short f2bf(float f) {
  union { float f; unsigned int u; } v; v.f = f;
  unsigned int r = v.u + 0x7fffu + ((v.u >> 16) & 1u);  // RNE
  return (unsigned short)(r >> 16);
}

__device__ __forceinline__ float bf2f(unsigned short s) {
  union { unsigned int u; float f; } v; v.u = ((unsigned int)s) << 16;
  return v.f;
}

__device__ __forceinline__ void async16(const unsigned short* g, unsigned short* l) {
  auto gp = (const __attribute__((address_space(1))) unsigned int*)(uintptr_t)g;
  auto lp = (__attribute__((address_space(3))) unsigned int*)(unsigned int)(uintptr_t)l;
  __builtin_amdgcn_global_load_lds(gp, lp, 16, 0, 0);
}

// fast transcendentals: v_exp_f32 (2^x) + v_rcp_f32; rel err ~1e-6,
// negligible vs bf16-GEMM absmax 0.031.
__device__ __forceinline__ float sigm(float v) {
  return __builtin_amdgcn_rcpf(1.f + __builtin_amdgcn_exp2f(-1.44269504088896f * v));
}
__device__ __forceinline__ float tanh_f(float v) {
  return 1.f - 2.f * __builtin_amdgcn_rcpf(1.f + __builtin_amdgcn_exp2f(2.88539008177793f * v));
}

// ---------------- merged prep: casts + weight transposes (one dispatch) -----

__global__ __launch_bounds__(256) void prep(
    const float* __restrict__ h0, const float* __restrict__ x,
    unsigned short* __restrict__ Ah, unsigned short* __restrict__ Ax,
    const float* __restrict__ Wh, const float* __restrict__ Wx,
    unsigned short* __restrict__ Wth, unsigned short* __restrict__ Wtx) {
  __shared__ float tile[32][33];
  const int bid = blockIdx.x;
  if (bid < 16384) {
    const float* in = (bid >= 8192) ? x : h0;
    unsigned short* out = (bid >= 8192) ? Ax : Ah;
    int i = ((bid & 8191) * 256 + threadIdx.x) * 4;
    float4 v = *(const float4*)(in + i);
    ushort4 o;
    o.x = f2bf(v.x); o.y = f2bf(v.y); o.z = f2bf(v.z); o.w = f2bf(v.w);
    *(ushort4*)(out + i) = o;
  } else {
    int b2 = bid - 16384;
    const float* W = (b2 >= 4096) ? Wx : Wh;
    unsigned short* Wt = (b2 >= 4096) ? Wtx : Wth;
    int r = b2 & 4095;
    int n0 = (r & 127) * 32;
    int k0 = (r >> 7) * 32;
    int tx = threadIdx.x & 31;
    int ty = threadIdx.x >> 5;
#pragma unroll
    for (int i = 0; i < 32; i += 8)
      tile[ty + i][tx] = W[(size_t)(k0 + ty + i) * N4 + n0 + tx];
    __syncthreads();
#pragma unroll
    for (int i = 0; i < 32; i += 8)
      Wt[(size_t)(n0 + ty + i) * KDIM + k0 + tx] = f2bf(tile[tx][ty + i]);
  }
}

// ---------------- bf16 MFMA GEMM (R0 bench-verified: 130 us, MfmaUtil 46%) --
// 256x256 tile, BK=64, 512 thr = 8 waves (2M x 4N), wave tile 128x64.
// LDS 128 KiB double-buffered.  Rotation swizzle.  4 phases/tile, each
// {ds_read subtile; 2 stage slices of t+1; setprio MFMA; vmcnt(4)+barrier}.
// Deadline ledger: stages issued at t-P0..P3 are forced 3..4 phase-waits
// later, exactly before their consuming phase; never drains to 0.

__global__ __launch_bounds__(512, 2) void gemm_bf16(
    const unsigned short* __restrict__ Ah, const unsigned short* __restrict__ Wth,
    unsigned short* __restrict__ Uh,
    const unsigned short* __restrict__ Ax, const unsigned short* __restrict__ Wtx,
    unsigned short* __restrict__ Ux, int row0) {
  const unsigned short* A; const unsigned short* W; unsigned short* U;
  if (blockIdx.z == 0) { A = Ah; W = Wth; U = Uh; } else { A = Ax; W = Wtx; U = Ux; }

  __shared__ unsigned short ldsA[2 * 256 * 64];
  __shared__ unsigned short ldsB[2 * 256 * 64];

  const int tid = threadIdx.x;
  const int wave = tid >> 6;
  const int lane = tid & 63;
  const int wm2 = wave >> 2;  // 0..1 (M half)
  const int wn4 = wave & 3;   // 0..3 (N quarter)

  // bijective XCD swizzle (m204)
  const int gx = N4 / 256;  // 16
  const int nwg = gx * (int)gridDim.y;
  const int f = (int)blockIdx.y * gx + (int)blockIdx.x;
  const int qq = nwg >> 3, rr = nwg & 7;
  const int xcd = f & 7, idx = f >> 3;
  const int wg = (xcd < rr) ? (xcd * (qq + 1) + idx)
                            : (rr * (qq + 1) + (xcd - rr) * qq + idx);
  const int bx = wg & (gx - 1);
  const int by = wg / gx;

  const int m0 = row0 + by * 256;
  const int n0 = bx * 256;

  // staging geometry: each wave-load covers 8 rows (64 lanes x 16B)
  const int r8 = lane >> 3;
  const int c8 = lane & 7;
  const int g8 = ((c8 - r8) & 7) * 8;  // element offset of logical chunk
  // per-wave 32-row regions, split by consumption deadline
  const int aE = (wave & 3) * 16 + (wave >> 2) * 128;  // A rows, deadline t+1-P0
  const int aL = aE + 64;                              // A rows, deadline t+1-P2
  const int bE = (wave >> 1) * 64 + (wave & 1) * 16;   // B rows, deadline t+1-P0
  const int bL = bE + 32;                              // B rows, deadline t+1-P1

  const unsigned short* gAe = A + (size_t)(m0 + aE + r8) * KDIM + g8;
  const unsigned short* gAl = A + (size_t)(m0 + aL + r8) * KDIM + g8;
  const unsigned short* gBe = W + (size_t)(n0 + bE + r8) * KDIM + g8;
  const unsigned short* gBl = W + (size_t)(n0 + bL + r8) * KDIM + g8;

  // fragment read offsets (elements). row = base + mi*16 + lq, chunk q = kk*4+lh,
  // physical slot = (q + row)&7 ; bases are multiples of 8 so slot = (q+lq)&7.
  const int lq = lane & 15, lh = lane >> 4;
  const int offA0 = (wm2 * 128 + lq) * 64 + ((lh + lq) & 7) * 8;
  const int offA1 = (wm2 * 128 + lq) * 64 + ((4 + lh + lq) & 7) * 8;
  const int offB0 = (wn4 * 64 + lq) * 64 + ((lh + lq) & 7) * 8;
  const int offB1 = (wn4 * 64 + lq) * 64 + ((4 + lh + lq) & 7) * 8;

  float4v acc[8][4];
  float4v zero = {0.f, 0.f, 0.f, 0.f};
#pragma unroll
  for (int i = 0; i < 8; ++i)
#pragma unroll
    for (int j = 0; j < 4; ++j) acc[i][j] = zero;

  // prologue: stage tile 0, deadline-ordered; require aE,bE done (allow bL,aL)
  async16(gAe, ldsA + aE * 64);
  async16(gAe + 8 * KDIM, ldsA + (aE + 8) * 64);
  async16(gBe, ldsB + bE * 64);
  async16(gBe + 8 * KDIM, ldsB + (bE + 8) * 64);
  async16(gBl, ldsB + bL * 64);
  async16(gBl + 8 * KDIM, ldsB + (bL + 8) * 64);
  async16(gAl, ldsA + aL * 64);
  async16(gAl + 8 * KDIM, ldsA + (aL + 8) * 64);
  asm volatile("s_waitcnt vmcnt(4)\n\ts_barrier" ::: "memory");

  short8 aF[4][2], bF[4][2];

#pragma unroll 2
  for (int t = 0; t < KDIM / 64; ++t) {
    const unsigned short* sA = ldsA + (t & 1) * 16384;
    const unsigned short* sB = ldsB + (t & 1) * 16384;
    unsigned short* dA = (unsigned short*)ldsA + ((t + 1) & 1) * 16384;
    unsigned short* dB = (unsigned short*)ldsB + ((t + 1) & 1) * 16384;
    const int k2 = (t + 1) * 64;  // ghost read at t=15 stays inside d_ws

    // ---- P0: read a[0..3], b[0,1]; stage A-early(t+1); MFMA Q0 ----
#pragma unroll
    for (int mi = 0; mi < 4; ++mi) {
      aF[mi][0] = *(const short8*)(sA + offA0 + mi * 1024);
      aF[mi][1] = *(const short8*)(sA + offA1 + mi * 1024);
    }
#pragma unroll
    for (int ni = 0; ni < 2; ++ni) {
      bF[ni][0] = *(const short8*)(sB + offB0 + ni * 1024);
      bF[ni][1] = *(const short8*)(sB + offB1 + ni * 1024);
    }
    async16(gAe + k2, dA + aE * 64);
    async16(gAe + k2 + 8 * KDIM, dA + (aE + 8) * 64);
    __builtin_amdgcn_s_setprio(1);
#pragma unroll
    for (int kk = 0; kk < 2; ++kk)
#pragma unroll
      for (int mi = 0; mi < 4; ++mi)
#pragma unroll
        for (int ni = 0; ni < 2; ++ni)
          acc[mi][ni] = __builtin_amdgcn_mfma_f32_16x16x32_bf16(aF[mi][kk], bF[ni][kk], acc[mi][ni], 0, 0, 0);
    __builtin_amdgcn_s_setprio(0);
    asm volatile("s_waitcnt vmcnt(4)\n\ts_barrier" ::: "memory");

    // ---- P1: read b[2,3]; stage B-early(t+1); MFMA Q1 ----
#pragma unroll
    for (int ni = 0; ni < 2; ++ni) {
      bF[2 + ni][0] = *(const short8*)(sB + offB0 + (2 + ni) * 1024);
      bF[2 + ni][1] = *(const short8*)(sB + offB1 + (2 + ni) * 1024);
    }
    async16(gBe + k2, dB + bE * 64);
    async16(gBe + k2 + 8 * KDIM, dB + (bE + 8) * 64);
    __builtin_amdgcn_s_setprio(1);
#pragma unroll
    for (int kk = 0; kk < 2; ++kk)
#pragma unroll
      for (int mi = 0; mi < 4; ++mi)
#pragma unroll
        for (int ni = 0; ni < 2; ++ni)
          acc[mi][2 + ni] = __builtin_amdgcn_mfma_f32_16x16x32_bf16(aF[mi][kk], bF[2 + ni][kk], acc[mi][2 + ni], 0, 0, 0);
    __builtin_amdgcn_s_setprio(0);
    asm volatile("s_waitcnt vmcnt(4)\n\ts_barrier" ::: "memory");

    // ---- P2: read a[4..7] (reuse aF); stage B-late(t+1); MFMA Q2 ----
#pragma unroll
    for (int mi = 0; mi < 4; ++mi) {
      aF[mi][0] = *(const short8*)(sA + offA0 + (4 + mi) * 1024);
      aF[mi][1] = *(const short8*)(sA + offA1 + (4 + mi) * 1024);
    }
    async16(gBl + k2, dB + bL * 64);
    async16(gBl + k2 + 8 * KDIM, dB + (bL + 8) * 64);
    __builtin_amdgcn_s_setprio(1);
#pragma unroll
    for (int kk = 0; kk < 2; ++kk)
#pragma unroll
      for (int mi = 0; mi < 4; ++mi)
#pragma unroll
        for (int ni = 0; ni < 2; ++ni)
          acc[4 + mi][ni] = __builtin_amdgcn_mfma_f32_16x16x32_bf16(aF[mi][kk], bF[ni][kk], acc[4 + mi][ni], 0, 0, 0);
    __builtin_amdgcn_s_setprio(0);
    asm volatile("s_waitcnt vmcnt(4)\n\ts_barrier" ::: "memory");

    // ---- P3: stage A-late(t+1); MFMA Q3 ----
    async16(gAl + k2, dA + aL * 64);
    async16(gAl + k2 + 8 * KDIM, dA + (aL + 8) * 64);
    __builtin_amdgcn_s_setprio(1);
#pragma unroll
    for (int kk = 0; kk < 2; ++kk)
#pragma unroll
      for (int mi = 0; mi < 4; ++mi)
#pragma unroll
        for (int ni = 0; ni < 2; ++ni)
          acc[4 + mi][2 + ni] = __builtin_amdgcn_mfma_f32_16x16x32_bf16(aF[mi][kk], bF[2 + ni][kk], acc[4 + mi][2 + ni], 0, 0, 0);
    __builtin_amdgcn_s_setprio(0);
    asm volatile("s_waitcnt vmcnt(4)\n\ts_barrier" ::: "memory");
  }
  asm volatile("s_waitcnt vmcnt(0)" ::: "memory");  // drain ghost stages before endpgm

  // epilogue: C/D layout col = lane&15, row = (lane>>4)*4 + reg; store bf16
  const int colc = lane & 15;
  const int rowq = (lane >> 4) * 4;
  unsigned short* Ub = U + (size_t)(by * 256 + wm2 * 128 + rowq) * N4 + n0 + wn4 * 64 + colc;
#pragma unroll
  for (int mi = 0; mi < 8; ++mi)
#pragma unroll
    for (int r = 0; r < 4; ++r) {
      unsigned short* Urow = Ub + (size_t)(mi * 16 + r) * N4;
#pragma unroll
      for (int ni = 0; ni < 4; ++ni) Urow[ni * 16] = f2bf(acc[mi][ni][r]);
    }
}

// ---------------- fused LN + LSTM pointwise, 2 rows/block, 16B loads --------
// 256 thr = 4 waves; row = t>>7 (waves 0,1 -> row A; 2,3 -> row B);
// u = t&127 owns h-indices [u*8, u*8+8).  Per mat, per gate g: one short8
// load at element g*1024 + u*8 -> gate alignment preserved with 16B loads.

__global__ __launch_bounds__(256) void fused_ln_lstm(
    const unsigned short* __restrict__ Uh, const unsigned short* __restrict__ Ux,
    const float* __restrict__ c0, const float* __restrict__ bias,
    const float* __restrict__ g1, const float* __restrict__ b1,
    const float* __restrict__ g2, const float* __restrict__ b2,
    const float* __restrict__ g3, const float* __restrict__ b3,
    float* __restrict__ h1o, float* __restrict__ c1o, int row0) {
  const int t = threadIdx.x;
  const int lane = t & 63;
  const int wv = t >> 6;        // 0..3
  const int row = t >> 7;       // 0..1
  const int u = t & 127;        // lane-in-row
  const size_t rloc = (size_t)blockIdx.x * 2 + row;
  const size_t rabs = rloc + (size_t)row0;

  const short8* uh = (const short8*)(Uh + rloc * N4);
  const short8* ux = (const short8*)(Ux + rloc * N4);
  const float4* c0p = (const float4*)(c0 + rabs * KDIM);
  float4 c0a = c0p[u * 2];      // issue early
  float4 c0b = c0p[u * 2 + 1];

  float vh[4][8], vx[4][8];
  float sh = 0.f, qh = 0.f, sx = 0.f, qx = 0.f;
#pragma unroll
  for (int g = 0; g < 4; ++g) {
    short8 a = uh[g * 128 + u];
    short8 b = ux[g * 128 + u];
#pragma unroll
    for (int e = 0; e < 8; ++e) {
      float fa = bf2f((unsigned short)a[e]); vh[g][e] = fa; sh += fa; qh += fa * fa;
      float fb = bf2f((unsigned short)b[e]); vx[g][e] = fb; sx += fb; qx += fb * fb;
    }
  }
  __shared__ float red[4][4];
#pragma unroll
  for (int o = 32; o > 0; o >>= 1) {
    sh += __shfl_down(sh, o); qh += __shfl_down(qh, o);
    sx += __shfl_down(sx, o); qx += __shfl_down(qx, o);
  }
  if (lane == 0) { red[wv][0] = sh; red[wv][1] = qh; red[wv][2] = sx; red[wv][3] = qx; }
  __syncthreads();
  sh = red[row * 2][0] + red[row * 2 + 1][0];
  qh = red[row * 2][1] + red[row * 2 + 1][1];
  sx = red[row * 2][2] + red[row * 2 + 1][2];
  qx = red[row * 2][3] + red[row * 2 + 1][3];
  const float inv4 = 1.f / 4096.f;
  const float muh = sh * inv4, mux = sx * inv4;
  const float rsh = rsqrtf(qh * inv4 - muh * muh + 1e-5f);
  const float rsx = rsqrtf(qx * inv4 - mux * mux + 1e-5f);

  // gates in-place: vh[g][e] = LN1(vh)+LN2(vx)+bias
#pragma unroll
  for (int g = 0; g < 4; ++g) {
    int j4 = g * 256 + u * 2;  // float4 index of element g*1024 + u*8
    float4 G1a = ((const float4*)g1)[j4], G1b = ((const float4*)g1)[j4 + 1];
    float4 B1a = ((const float4*)b1)[j4], B1b = ((const float4*)b1)[j4 + 1];
    float4 G2a = ((const float4*)g2)[j4], G2b = ((const float4*)g2)[j4 + 1];
    float4 B2a = ((const float4*)b2)[j4], B2b = ((const float4*)b2)[j4 + 1];
    float4 BBa = ((const float4*)bias)[j4], BBb = ((const float4*)bias)[j4 + 1];
    float G1v[8] = {G1a.x, G1a.y, G1a.z, G1a.w, G1b.x, G1b.y, G1b.z, G1b.w};
    float B1v[8] = {B1a.x, B1a.y, B1a.z, B1a.w, B1b.x, B1b.y, B1b.z, B1b.w};
    float G2v[8] = {G2a.x, G2a.y, G2a.z, G2a.w, G2b.x, G2b.y, G2b.z, G2b.w};
    float B2v[8] = {B2a.x, B2a.y, B2a.z, B2a.w, B2b.x, B2b.y, B2b.z, B2b.w};
    float BBv[8] = {BBa.x, BBa.y, BBa.z, BBa.w, BBb.x, BBb.y, BBb.z, BBb.w};
#pragma unroll
    for (int e = 0; e < 8; ++e)
      vh[g][e] = (vh[g][e] - muh) * rsh * G1v[e] + B1v[e]
               + (vx[g][e] - mux) * rsx * G2v[e] + B2v[e] + BBv[e];
  }

  float c0v[8] = {c0a.x, c0a.y, c0a.z, c0a.w, c0b.x, c0b.y, c0b.z, c0b.w};
  float c1v[8];
  float sc = 0.f, qc = 0.f;
#pragma unroll
  for (int e = 0; e < 8; ++e) {
    float cv = sigm(vh[0][e]) * c0v[e] + sigm(vh[1][e]) * tanh_f(vh[3][e]);
    c1v[e] = cv; sc += cv; qc += cv * cv;
  }
#pragma unroll
  for (int o = 32; o > 0; o >>= 1) { sc += __shfl_down(sc, o); qc += __shfl_down(qc, o); }
  __syncthreads();  // protect `red` reuse
  if (lane == 0) { red[wv][0] = sc; red[wv][1] = qc; }
  __syncthreads();
  sc = red[row * 2][0] + red[row * 2 + 1][0];
  qc = red[row * 2][1] + red[row * 2 + 1][1];
  const float invH = 1.f / 1024.f;
  const float muc = sc * invH;
  const float rsc = rsqrtf(qc * invH - muc * muc + 1e-5f);

  float4 G3a = ((const float4*)g3)[u * 2], G3b = ((const float4*)g3)[u * 2 + 1];
  float4 B3a = ((const float4*)b3)[u * 2], B3b = ((const float4*)b3)[u * 2 + 1];
  float G3v[8] = {G3a.x, G3a.y, G3a.z, G3a.w, G3b.x, G3b.y, G3b.z, G3b.w};
  float B3v[8] = {B3a.x, B3a.y, B3a.z, B3a.w, B3b.x, B3b.y, B3b.z, B3b.w};
  float h1v[8];
#pragma unroll
  for (int e = 0; e < 8; ++e)
    h1v[e] = sigm(vh[2][e]) * tanh_f((c1v[e] - muc) * rsc * G3v[e] + B3v[e]);

  float4* hp = (float4*)(h1o + rabs * KDIM);
  float4* cp = (float4*)(c1o + rabs * KDIM);
  float4 o0 = {h1v[0], h1v[1], h1v[2], h1v[3]};
  float4 o1 = {h1v[4], h1v[5], h1v[6], h1v[7]};
  float4 o2 = {c1v[0], c1v[1], c1v[2], c1v[3]};
  float4 o3 = {c1v[4], c1v[5], c1v[6], c1v[7]};
  hp[u * 2] = o0; hp[u * 2 + 1] = o1;
  cp[u * 2] = o2; cp[u * 2 + 1] = o3;
}

// ---------------- launch ----------------

extern "C" void kernel_launch(void* const* d_in, const int* in_sizes, int n_in,
                              void* d_out, int out_size, void* d_ws, size_t ws_size,
                              hipStream_t stream) {
  const float* x    = (const float*)d_in[0];
  const float* h0   = (const float*)d_in[1];
  const float* c0   = (const float*)d_in[2];
  const float* Wh   = (const float*)d_in[3];
  const float* Wx   = (const float*)d_in[4];
  const float* bias = (const float*)d_in[5];
  const float* g1   = (const float*)d_in[6];
  const float* b1   = (const float*)d_in[7];
  const float* g2   = (const float*)d_in[8];
  const float* b2   = (const float*)d_in[9];
  const float* g3   = (const float*)d_in[10];
  const float* b3   = (const float*)d_in[11];
  float* h1o = (float*)d_out;
  float* c1o = h1o + (size_t)B_ROWS * KDIM;

  // ws layout: Ah bf16 | Ax bf16 | Wth bf16 | Wtx bf16 | U (chunked bf16 gate bufs)
  unsigned short* Ah  = (unsigned short*)d_ws;
  unsigned short* Ax  = Ah + (size_t)B_ROWS * KDIM;
  unsigned short* Wth = Ax + (size_t)B_ROWS * KDIM;
  unsigned short* Wtx = Wth + (size_t)N4 * KDIM;
  unsigned short* U = Wtx + (size_t)N4 * KDIM;
  size_t used = ((size_t)B_ROWS * KDIM * 2 + (size_t)N4 * KDIM * 2) * sizeof(unsigned short);
  size_t rem = ws_size > used ? ws_size - used : 0;
  int chunk = (int)(rem / ((size_t)2 * N4 * sizeof(unsigned short)));
  chunk &= ~255;
  if (chunk > B_ROWS) chunk = B_ROWS;
  if (chunk < 256) chunk = 256;  // assume ws_size is at least ~64MB

  prep<<<24576, 256, 0, stream>>>(h0, x, Ah, Ax, Wh, Wx, Wth, Wtx);

  for (int r0 = 0; r0 < B_ROWS; r0 += chunk) {
    int rows = chunk;
    if (r0 + rows > B_ROWS) rows = B_ROWS - r0;
    unsigned short* Uh = U;
    unsigned short* Ux = U + (size_t)rows * N4;
    gemm_bf16<<<dim3(N4 / 256, rows / 256, 2), 512, 0, stream>>>(Ah, Wth, Uh, Ax, Wtx, Ux, r0);
    fused_ln_lstm<<<rows / 2, 256, 0, stream>>>(Uh, Ux, c0, bias, g1, b1, g2, b2, g3, b3, h1o, c1o, r0);
  }
}